// Round 2
// baseline (192.863 us; speedup 1.0000x reference)
//
#include <hip/hip_runtime.h>

// RelationalGraphConvLayer: out[b,m,u] = relu(sum_e (adj[b,e]@feat[b]) @ ker[b,e])
// B=256, E=5, N=128, ATOM=64, UNITS=128, fp32 in/out, bf16 MFMA compute.
//
// R2 design: grid=1024 (4 blocks/sample, 32 rows each), block=256 = 4 waves
// arranged (row-tile mw in {0,1}) x (u-half uw in {0,1}). Each wave computes
// matmul1 (Y = adj_e @ feat) for its 16 rows redundantly and matmul2 only for
// its 64-unit half. No kerT LDS (ker B-frags straight from global, L2-deduped),
// no in-loop barriers, YB wave-private. 16 waves/CU via __launch_bounds__(256,4).

typedef __attribute__((ext_vector_type(8))) short s8v;  // 8 x bf16 MFMA A/B frag
typedef __attribute__((ext_vector_type(4))) float f4v;  // MFMA C/D frag / float4

__device__ __forceinline__ short f2bf(float f) {
    // fp32 -> bf16 round-to-nearest-even (inputs finite)
    unsigned u = __builtin_bit_cast(unsigned, f);
    u += 0x7FFFu + ((u >> 16) & 1u);
    return (short)(u >> 16);
}

__global__ __launch_bounds__(256, 4)
void rgc_kernel(const float* __restrict__ adj,
                const float* __restrict__ feat,
                const float* __restrict__ ker,
                float* __restrict__ out)
{
    // featT row stride 136 shorts (272B = 68 banks = 4 mod 32): b128 reads are
    // <=2-way bank aliased (free per m136). YB same idea (72 shorts).
    __shared__ __align__(16) short featT[64][136];   // featT[d][n] = feat[n][d]
    __shared__ __align__(16) short YB[4][16][72];    // per-wave Y scratch [m][d]

    const int b    = blockIdx.x >> 2;
    const int rg   = blockIdx.x & 3;     // row group: rows [32*rg, 32*rg+32)
    const int tid  = threadIdx.x;
    const int w    = tid >> 6;           // wave 0..3
    const int mw   = w >> 1;             // row tile within group (16 rows)
    const int uw   = w & 1;              // u half (64 units)
    const int lane = tid & 63;
    const int c16  = lane & 15;
    const int quad = lane >> 4;

    const float* adjB  = adj  + (size_t)b * (5 * 128 * 128);
    const float* featB = feat + (size_t)b * (128 * 64);
    const float* kerB  = ker  + (size_t)b * (5 * 64 * 128);
    float*       outB  = out  + (size_t)b * (128 * 128);

    // ---- stage featT (bf16, transposed) once: 8192 floats / 256 thr ----
    {
        f4v fv[8];
        #pragma unroll
        for (int i = 0; i < 8; ++i)
            fv[i] = *(const f4v*)(featB + (i * 256 + tid) * 4);
        #pragma unroll
        for (int i = 0; i < 8; ++i) {
            int g = i * 256 + tid;
            int n = g >> 4, d0 = (g & 15) << 2;
            #pragma unroll
            for (int j = 0; j < 4; ++j)
                featT[d0 + j][n] = f2bf(fv[i][j]);
        }
    }
    __syncthreads();  // the only barrier in the kernel

    const int rowS = 32 * rg + 16 * mw;                       // sample-row base
    const float* ap0 = adjB + (rowS + c16) * 128 + 8 * quad;  // A-frag base
    const float* kp0 = kerB + (8 * quad) * 128 + 64 * uw + c16;
    short (*YBw)[72] = YB[w];

    f4v oacc[4] = {};  // this wave's 16 rows x 64 units (4 u16 tiles)

    for (int e = 0; e < 5; ++e) {
        // ---- adjacency A-frags: 16 rows straight from global ----
        const float* ap = ap0 + e * (128 * 128);
        f4v a0[4], a1[4];
        #pragma unroll
        for (int k16 = 0; k16 < 4; ++k16) {
            a0[k16] = *(const f4v*)(ap + 32 * k16);
            a1[k16] = *(const f4v*)(ap + 32 * k16 + 4);
        }

        // ---- matmul1: Y[16 rows] = adj_e @ feat  (K=128) ----
        f4v yacc[4] = {};
        #pragma unroll
        for (int k16 = 0; k16 < 4; ++k16) {
            s8v af;
            #pragma unroll
            for (int j = 0; j < 4; ++j) af[j] = f2bf(a0[k16][j]);
            #pragma unroll
            for (int j = 0; j < 4; ++j) af[4 + j] = f2bf(a1[k16][j]);
            #pragma unroll
            for (int d16 = 0; d16 < 4; ++d16) {
                s8v bf = *(const s8v*)&featT[16 * d16 + c16][32 * k16 + 8 * quad];
                yacc[d16] = __builtin_amdgcn_mfma_f32_16x16x32_bf16(af, bf, yacc[d16], 0, 0, 0);
            }
        }

        // ---- Y: C/D layout -> A-operand layout via wave-private LDS ----
        #pragma unroll
        for (int d16 = 0; d16 < 4; ++d16)
            #pragma unroll
            for (int r = 0; r < 4; ++r)
                YBw[4 * quad + r][16 * d16 + c16] = f2bf(yacc[d16][r]);
        s8v y0 = *(const s8v*)&YBw[c16][8 * quad];
        s8v y1 = *(const s8v*)&YBw[c16][32 + 8 * quad];

        // ---- matmul2: oacc += Y @ ker_e, this wave's u-half (K=64) ----
        const float* kp = kp0 + e * (64 * 128);
        #pragma unroll
        for (int u16 = 0; u16 < 4; ++u16) {
            s8v b0, b1;
            #pragma unroll
            for (int j = 0; j < 8; ++j) {
                b0[j] = f2bf(kp[j * 128 + 16 * u16]);          // k = 8q+j
                b1[j] = f2bf(kp[(32 + j) * 128 + 16 * u16]);   // k = 32+8q+j
            }
            oacc[u16] = __builtin_amdgcn_mfma_f32_16x16x32_bf16(y0, b0, oacc[u16], 0, 0, 0);
            oacc[u16] = __builtin_amdgcn_mfma_f32_16x16x32_bf16(y1, b1, oacc[u16], 0, 0, 0);
        }
    }

    // ---- epilogue: relu + store ----
    #pragma unroll
    for (int u16 = 0; u16 < 4; ++u16)
        #pragma unroll
        for (int r = 0; r < 4; ++r)
            outB[(rowS + 4 * quad + r) * 128 + 64 * uw + 16 * u16 + c16] =
                fmaxf(oacc[u16][r], 0.f);
}

extern "C" void kernel_launch(void* const* d_in, const int* in_sizes, int n_in,
                              void* d_out, int out_size, void* d_ws, size_t ws_size,
                              hipStream_t stream)
{
    const float* adj  = (const float*)d_in[0];
    const float* feat = (const float*)d_in[1];
    const float* ker  = (const float*)d_in[2];
    rgc_kernel<<<1024, 256, 0, stream>>>(adj, feat, ker, (float*)d_out);
}

// Round 3
// 172.989 us; speedup vs baseline: 1.1149x; 1.1149x over previous
//
#include <hip/hip_runtime.h>

// RelationalGraphConvLayer: out[b,m,u] = relu(sum_e (adj[b,e]@feat[b]) @ ker[b,e])
// B=256, E=5, N=128, ATOM=64, UNITS=128, fp32 in/out, bf16 MFMA compute.
//
// R3: grid=512 (2 blocks/sample, 64 rows each), block=512 = 8 waves =
// (4 row-tiles) x (2 u-halves). ker/feat staged in LDS with XOR chunk swizzle
// (16B chunk c of row r stored at c^(r&7)) -> conflict-free b128 reads AND
// writes (R1's 6.77M conflict cycles were the 16-way kerT column writes).
// kerT double-buffered, 1 barrier/e. 2 blocks/CU (LDS 56KB) = 16 waves/CU.

typedef __attribute__((ext_vector_type(8))) short s8v;  // 8 x bf16 MFMA A/B frag
typedef __attribute__((ext_vector_type(4))) float f4v;  // MFMA C/D frag / float4

__device__ __forceinline__ short f2bf(float f) {
    unsigned u = __builtin_bit_cast(unsigned, f);
    u += 0x7FFFu + ((u >> 16) & 1u);
    return (short)(u >> 16);
}

__global__ __launch_bounds__(512, 4)
void rgc_kernel(const float* __restrict__ adj,
                const float* __restrict__ feat,
                const float* __restrict__ ker,
                float* __restrict__ out)
{
    // All arrays chunk-swizzled: element [row][col] lives at
    // row*W + ((col>>3) ^ (row&7))*8 + (col&7). Rows are 16B-aligned, banks
    // spread by the XOR. No padding needed.
    __shared__ __align__(16) short featT_s[64 * 128];    // [d][n] 16 KB
    __shared__ __align__(16) short kerT_s[2][128 * 64];  // [u][d] 2x16 KB
    __shared__ __align__(16) short YB_s[8][16 * 64];     // per-wave [m][d] 16 KB

    const int bs   = blockIdx.x & 255;   // sample
    const int half = blockIdx.x >> 8;    // row half: same-XCD pairing with +256
    const int tid  = threadIdx.x;
    const int w    = tid >> 6;           // wave 0..7
    const int mw   = w >> 1;             // row tile (16 rows)
    const int uw   = w & 1;              // u half (64 units)
    const int lane = tid & 63;
    const int c16  = lane & 15;
    const int quad = lane >> 4;

    const float* adjB  = adj  + (size_t)bs * (5 * 128 * 128);
    const float* featB = feat + (size_t)bs * (128 * 64);
    const float* kerB  = ker  + (size_t)bs * (5 * 64 * 128);
    float*       outB  = out  + (size_t)bs * (128 * 128);

    const int rowS = 64 * half + 16 * mw;

    // ---- stage featT[d][n] = feat[n][d], chunk-swizzled, once ----
    // thread covers chunks (d=lane, cn=8s+w): 8 strided scalar loads each,
    // per-instruction the wave reads 256B contiguous (lane-consecutive d).
    #pragma unroll
    for (int s = 0; s < 2; ++s) {
        const int d  = lane;
        const int cn = 8 * s + w;
        float v[8];
        #pragma unroll
        for (int j = 0; j < 8; ++j) v[j] = featB[(8 * cn + j) * 64 + d];
        s8v fr;
        #pragma unroll
        for (int j = 0; j < 8; ++j) fr[j] = f2bf(v[j]);
        *(s8v*)&featT_s[d * 128 + ((cn ^ (d & 7)) << 3)] = fr;
    }
    // ---- stage kerT[0]: kerT[u][d] = ker[0][d][u], chunk-swizzled ----
    {
        const int u = tid & 127;
        #pragma unroll
        for (int s = 0; s < 2; ++s) {
            const int cd = 4 * s + mw;
            float v[8];
            #pragma unroll
            for (int j = 0; j < 8; ++j) v[j] = kerB[(8 * cd + j) * 128 + u];
            s8v fr;
            #pragma unroll
            for (int j = 0; j < 8; ++j) fr[j] = f2bf(v[j]);
            *(s8v*)&kerT_s[0][u * 64 + (((cd ^ (u & 7))) << 3)] = fr;
        }
    }
    __syncthreads();

    f4v oacc[4] = {};  // 16 rows x 64 units (4 u16 tiles)

    #pragma unroll
    for (int e = 0; e < 5; ++e) {
        const int buf = e & 1;

        // ---- adjacency A-frags: this wave's 16 rows straight from global ----
        const float* ap = adjB + e * 16384 + (rowS + c16) * 128 + 8 * quad;
        f4v a0[4], a1[4];
        #pragma unroll
        for (int k16 = 0; k16 < 4; ++k16) {
            a0[k16] = *(const f4v*)(ap + 32 * k16);
            a1[k16] = *(const f4v*)(ap + 32 * k16 + 4);
        }
        // ---- issue next e's ker loads (latency hidden behind mm1) ----
        float kv[2][8];
        const int u = tid & 127;
        if (e < 4) {
            #pragma unroll
            for (int s = 0; s < 2; ++s) {
                const int cd = 4 * s + mw;
                #pragma unroll
                for (int j = 0; j < 8; ++j)
                    kv[s][j] = kerB[(e + 1) * 8192 + (8 * cd + j) * 128 + u];
            }
        }

        // ---- matmul1: Y[16 rows][64 d] = adj_e @ feat  (K=128) ----
        f4v yacc[4] = {};
        #pragma unroll
        for (int k16 = 0; k16 < 4; ++k16) {
            s8v af;
            #pragma unroll
            for (int j = 0; j < 4; ++j) af[j] = f2bf(a0[k16][j]);
            #pragma unroll
            for (int j = 0; j < 4; ++j) af[4 + j] = f2bf(a1[k16][j]);
            #pragma unroll
            for (int d16 = 0; d16 < 4; ++d16) {
                const int d = 16 * d16 + c16;
                s8v bf = *(const s8v*)
                    &featT_s[d * 128 + (((4 * k16 + quad) ^ (d & 7)) << 3)];
                yacc[d16] = __builtin_amdgcn_mfma_f32_16x16x32_bf16(af, bf, yacc[d16], 0, 0, 0);
            }
        }

        // ---- write next kerT (other buffer; no barrier needed in-iter) ----
        if (e < 4) {
            #pragma unroll
            for (int s = 0; s < 2; ++s) {
                const int cd = 4 * s + mw;
                s8v fr;
                #pragma unroll
                for (int j = 0; j < 8; ++j) fr[j] = f2bf(kv[s][j]);
                *(s8v*)&kerT_s[buf ^ 1][u * 64 + ((cd ^ (u & 7)) << 3)] = fr;
            }
        }

        // ---- Y: C/D layout -> A-operand layout via wave-private swizzled LDS ----
        short* YBw = YB_s[w];
        #pragma unroll
        for (int d16 = 0; d16 < 4; ++d16) {
            const int ch = 2 * d16 + (c16 >> 3);
            #pragma unroll
            for (int r = 0; r < 4; ++r) {
                const int m = 4 * quad + r;
                YBw[m * 64 + ((ch ^ (m & 7)) << 3) + (c16 & 7)] = f2bf(yacc[d16][r]);
            }
        }
        s8v y0 = *(const s8v*)&YBw[c16 * 64 + ((quad ^ (c16 & 7)) << 3)];
        s8v y1 = *(const s8v*)&YBw[c16 * 64 + (((4 + quad) ^ (c16 & 7)) << 3)];

        // ---- matmul2: oacc += Y @ ker_e for this wave's 64-unit half (K=64) ----
        #pragma unroll
        for (int u16 = 0; u16 < 4; ++u16) {
            const int uc = 64 * uw + 16 * u16 + c16;
            s8v b0 = *(const s8v*)&kerT_s[buf][uc * 64 + ((quad ^ (uc & 7)) << 3)];
            s8v b1 = *(const s8v*)&kerT_s[buf][uc * 64 + (((4 + quad) ^ (uc & 7)) << 3)];
            oacc[u16] = __builtin_amdgcn_mfma_f32_16x16x32_bf16(y0, b0, oacc[u16], 0, 0, 0);
            oacc[u16] = __builtin_amdgcn_mfma_f32_16x16x32_bf16(y1, b1, oacc[u16], 0, 0, 0);
        }

        if (e < 4) __syncthreads();  // kerT double-buffer rotation
    }

    // ---- epilogue: relu + store ----
    #pragma unroll
    for (int u16 = 0; u16 < 4; ++u16)
        #pragma unroll
        for (int r = 0; r < 4; ++r)
            outB[(rowS + 4 * quad + r) * 128 + 64 * uw + 16 * u16 + c16] =
                fmaxf(oacc[u16][r], 0.f);
}

extern "C" void kernel_launch(void* const* d_in, const int* in_sizes, int n_in,
                              void* d_out, int out_size, void* d_ws, size_t ws_size,
                              hipStream_t stream)
{
    const float* adj  = (const float*)d_in[0];
    const float* feat = (const float*)d_in[1];
    const float* ker  = (const float*)d_in[2];
    rgc_kernel<<<512, 512, 0, stream>>>(adj, feat, ker, (float*)d_out);
}